// Round 2
// baseline (1522.090 us; speedup 1.0000x reference)
//
#include <hip/hip_runtime.h>
#include <hip/hip_fp16.h>

#define RES 512
#define CHAN 16
#define HW (RES * RES)          // 262144 locations per plane
#define PLANE_F (CHAN * HW)     // fp32 floats per plane, original layout
#define CG 32                   // cells per axis for 3D binning
#define NCELLS (CG * CG * CG)   // 32768

// ---------------------------------------------------------------------------
// Pass 1: transpose + downconvert (3,16,512,512) fp32 -> (3,512,512,16) fp16.
// 16 channels at one (h,w) form a contiguous 32B block.
// ---------------------------------------------------------------------------
__global__ __launch_bounds__(256) void triplane_transpose_f16(
    const float* __restrict__ src, uint4* __restrict__ dst) {
  int b    = blockIdx.x;
  int p    = b >> 11;            // 2048 blocks per plane (512 h * 4 strips)
  int rem  = b & 2047;
  int h    = rem >> 2;
  int strip= rem & 3;
  int half = threadIdx.x & 1;
  int w    = (strip << 7) + (threadIdx.x >> 1);

  const float* s = src + (size_t)(p * CHAN + half * 8) * HW + h * RES + w;

  uint u[4];
#pragma unroll
  for (int k = 0; k < 4; ++k) {
    float f0 = s[(size_t)(2 * k + 0) * HW];
    float f1 = s[(size_t)(2 * k + 1) * HW];
    uint lo = (uint)__half_as_ushort(__float2half_rn(f0));
    uint hi = (uint)__half_as_ushort(__float2half_rn(f1));
    u[k] = lo | (hi << 16);
  }
  dst[((size_t)p * HW + h * RES + w) * 2 + half] = make_uint4(u[0], u[1], u[2], u[3]);
}

// ---------------------------------------------------------------------------
// Binning helpers
// ---------------------------------------------------------------------------
__device__ __forceinline__ unsigned part1by2(unsigned x) {
  x &= 0x3ff;
  x = (x | (x << 16)) & 0x030000FF;
  x = (x | (x << 8))  & 0x0300F00F;
  x = (x | (x << 4))  & 0x030C30C3;
  x = (x | (x << 2))  & 0x09249249;
  return x;
}

__device__ __forceinline__ int cell_coord(float v) {
  int c = (int)((v + 1.0f) * (0.5f * CG));
  return min(max(c, 0), CG - 1);
}

// Pass A: per-point Morton cell id + histogram
__global__ __launch_bounds__(256) void cell_hist(
    const float* __restrict__ xyz, int N,
    unsigned* __restrict__ cellid, unsigned* __restrict__ hist) {
  int p = blockIdx.x * 256 + threadIdx.x;
  if (p >= N) return;
  float x = xyz[3 * p + 0];
  float y = xyz[3 * p + 1];
  float z = xyz[3 * p + 2];
  int cx = cell_coord(x);
  int cy = cell_coord(y);
  int cz = cell_coord(z * 20.0f);    // z in [-0.05,0.05] -> [-1,1] (binning only)
  unsigned key = part1by2((unsigned)cx) | (part1by2((unsigned)cy) << 1) |
                 (part1by2((unsigned)cz) << 2);
  cellid[p] = key;
  atomicAdd(&hist[key], 1u);
}

// zero helper (avoid hipMemsetAsync inside capture)
__global__ __launch_bounds__(256) void zero_u32(unsigned* __restrict__ a, int n) {
  int i = blockIdx.x * 256 + threadIdx.x;
  if (i < n) a[i] = 0u;
}

// Pass B: exclusive scan of 32768 counts -> cursor (single workgroup)
__global__ __launch_bounds__(1024) void scan_cells(
    const unsigned* __restrict__ hist, unsigned* __restrict__ cursor) {
  __shared__ unsigned s[1024];
  int tid = threadIdx.x;
  unsigned local[32];
  unsigned sum = 0;
  int base = tid * 32;
#pragma unroll
  for (int i = 0; i < 32; ++i) { local[i] = hist[base + i]; sum += local[i]; }
  s[tid] = sum;
  __syncthreads();
  for (int d = 1; d < 1024; d <<= 1) {
    unsigned v = (tid >= d) ? s[tid - d] : 0u;
    __syncthreads();
    s[tid] += v;
    __syncthreads();
  }
  unsigned run = s[tid] - sum;       // exclusive prefix of this thread's chunk
#pragma unroll
  for (int i = 0; i < 32; ++i) { cursor[base + i] = run; run += local[i]; }
}

// Pass C: scatter (x, y, z, orig_idx) into cell-sorted order
__global__ __launch_bounds__(256) void cell_scatter(
    const float* __restrict__ xyz, const unsigned* __restrict__ cellid,
    unsigned* __restrict__ cursor, float4* __restrict__ sorted, int N) {
  int p = blockIdx.x * 256 + threadIdx.x;
  if (p >= N) return;
  unsigned key = cellid[p];
  unsigned pos = atomicAdd(&cursor[key], 1u);
  sorted[pos] = make_float4(xyz[3 * p + 0], xyz[3 * p + 1], xyz[3 * p + 2],
                            __int_as_float(p));
}

// ---------------------------------------------------------------------------
// Helper: 4 packed fp16 -> float4
// ---------------------------------------------------------------------------
__device__ __forceinline__ float4 h4_to_f4(uint2 u) {
  __half2 h0 = *reinterpret_cast<const __half2*>(&u.x);
  __half2 h1 = *reinterpret_cast<const __half2*>(&u.y);
  float2 f0 = __half22float2(h0);
  float2 f1 = __half22float2(h1);
  return make_float4(f0.x, f0.y, f1.x, f1.y);
}

__device__ __forceinline__ float4 bilerp_f16(
    const void* fm, int pl, int cq, float a, float b) {
  float u = (a + 1.0f) * 255.5f;
  float v = (b + 1.0f) * 255.5f;
  float x0 = floorf(u), y0 = floorf(v);
  float x1 = x0 + 1.0f, y1 = y0 + 1.0f;
  float wa = (x1 - u) * (y1 - v);
  float wb = (u - x0) * (y1 - v);
  float wc = (x1 - u) * (v - y0);
  float wd = (u - x0) * (v - y0);
  int x0i = (int)fminf(fmaxf(x0, 0.0f), 510.0f);
  int x1i = (int)fminf(fmaxf(x1, 1.0f), 511.0f);
  int y0i = (int)fminf(fmaxf(y0, 0.0f), 510.0f);
  int y1i = (int)fminf(fmaxf(y1, 1.0f), 511.0f);
  const uint2* base = (const uint2*)fm + (size_t)pl * (HW * 4);
  uint2 A = base[(size_t)(x0i * RES + y0i) * 4 + cq];
  uint2 B = base[(size_t)(x1i * RES + y0i) * 4 + cq];
  uint2 C = base[(size_t)(x0i * RES + y1i) * 4 + cq];
  uint2 D = base[(size_t)(x1i * RES + y1i) * 4 + cq];
  float4 fA = h4_to_f4(A), fB = h4_to_f4(B), fC = h4_to_f4(C), fD = h4_to_f4(D);
  float4 r;
  r.x = wa * fA.x + wb * fB.x + wc * fC.x + wd * fD.x;
  r.y = wa * fA.y + wb * fB.y + wc * fC.y + wd * fD.y;
  r.z = wa * fA.z + wb * fB.z + wc * fC.z + wd * fD.z;
  r.w = wa * fA.w + wb * fB.w + wc * fC.w + wd * fD.w;
  return r;
}

// ---------------------------------------------------------------------------
// Pass D: gather over cell-sorted points.  item = sp*12 + q.
// Bijective XCD-chunked swizzle keeps each XCD's blocks on a compact Morton
// subcube so per-XCD L2 sees a small, hot plane region.
// ---------------------------------------------------------------------------
__global__ __launch_bounds__(256) void triplane_gather_sorted(
    const float4* __restrict__ sorted, const void* __restrict__ fm,
    float* __restrict__ out, int n12, int nwg) {
  // bijective XCD swizzle (8 XCDs)
  int b   = blockIdx.x;
  int q8  = nwg >> 3;
  int r8  = nwg & 7;
  int xcd = b & 7;
  int i   = b >> 3;
  int sb  = (xcd < r8 ? xcd * (q8 + 1) : r8 * (q8 + 1) + (xcd - r8) * q8) + i;

  int item = sb * 256 + (int)threadIdx.x;
  if (item >= n12) return;

  int sp = item / 12;
  int q  = item - sp * 12;
  int s  = q >> 2;                    // segment 0,1,2
  int cq = q & 3;                     // channel quad

  float4 sx = sorted[sp];
  float x  = sx.x;
  float y  = sx.y;
  float zs = sx.z / 0.05f;            // exact reference semantics
  int   po = __float_as_int(sx.w);

  float a  = (s == 0) ? x : ((s == 1) ? y : zs);
  float bb = (s == 0) ? y : ((s == 1) ? zs : x);
  int   pl = (s == 0) ? 0 : ((s == 1) ? 2 : 1);

  float4 r = bilerp_f16(fm, pl, cq, a, bb);
  ((float4*)out)[(size_t)po * 12 + q] = r;
}

// ---------------------------------------------------------------------------
// Round-1 style gather (unsorted) — fallback if ws too small for sort buffers.
// ---------------------------------------------------------------------------
template <bool TRANSPOSED>
__global__ __launch_bounds__(256) void triplane_gather(
    const float* __restrict__ xyz, const void* __restrict__ fm,
    float* __restrict__ out, int n12) {
  int gid = blockIdx.x * 256 + threadIdx.x;
  if (gid >= n12) return;

  int p  = gid / 12;
  int q  = gid - p * 12;
  int s  = q >> 2;
  int cq = q & 3;

  float x = xyz[p * 3 + 0];
  float y = xyz[p * 3 + 1];
  float z = xyz[p * 3 + 2];
  float zs = z / 0.05f;

  float a  = (s == 0) ? x : ((s == 1) ? y : zs);
  float bb = (s == 0) ? y : ((s == 1) ? zs : x);
  int   pl = (s == 0) ? 0 : ((s == 1) ? 2 : 1);

  float4 r;
  if (TRANSPOSED) {
    r = bilerp_f16(fm, pl, cq, a, bb);
  } else {
    float u = (a + 1.0f) * 255.5f;
    float v = (bb + 1.0f) * 255.5f;
    float x0 = floorf(u), y0 = floorf(v);
    float x1 = x0 + 1.0f, y1 = y0 + 1.0f;
    float wa = (x1 - u) * (y1 - v);
    float wb = (u - x0) * (y1 - v);
    float wc = (x1 - u) * (v - y0);
    float wd = (u - x0) * (v - y0);
    int x0i = (int)fminf(fmaxf(x0, 0.0f), 510.0f);
    int x1i = (int)fminf(fmaxf(x1, 1.0f), 511.0f);
    int y0i = (int)fminf(fmaxf(y0, 0.0f), 510.0f);
    int y1i = (int)fminf(fmaxf(y1, 1.0f), 511.0f);
    const float* fbase = (const float*)fm + (size_t)pl * PLANE_F + (size_t)(cq * 4) * HW;
    float acc[4];
#pragma unroll
    for (int j = 0; j < 4; ++j) {
      const float* ch = fbase + (size_t)j * HW;
      float A = ch[x0i * RES + y0i];
      float B = ch[x1i * RES + y0i];
      float C = ch[x0i * RES + y1i];
      float D = ch[x1i * RES + y1i];
      acc[j] = wa * A + wb * B + wc * C + wd * D;
    }
    r = make_float4(acc[0], acc[1], acc[2], acc[3]);
  }
  ((float4*)out)[gid] = r;
}

extern "C" void kernel_launch(void* const* d_in, const int* in_sizes, int n_in,
                              void* d_out, int out_size, void* d_ws, size_t ws_size,
                              hipStream_t stream) {
  const float* xyz = (const float*)d_in[0];
  const float* fm  = (const float*)d_in[1];
  float* out = (float*)d_out;

  int N   = in_sizes[0] / 3;
  int n12 = N * 12;
  int grid = (n12 + 255) / 256;

  // workspace layout (bytes)
  size_t off_planes = 0;
  size_t sz_planes  = (size_t)3 * HW * CHAN * sizeof(unsigned short); // 24 MB
  size_t off_hist   = off_planes + sz_planes;
  size_t off_cursor = off_hist + (size_t)NCELLS * 4;
  size_t off_cellid = off_cursor + (size_t)NCELLS * 4;
  size_t off_sorted = off_cellid + (size_t)N * 4;
  size_t need_full  = off_sorted + (size_t)N * 16;

  char* ws = (char*)d_ws;

  if (ws_size >= need_full) {
    unsigned* hist   = (unsigned*)(ws + off_hist);
    unsigned* cursor = (unsigned*)(ws + off_cursor);
    unsigned* cellid = (unsigned*)(ws + off_cellid);
    float4*   sorted = (float4*)(ws + off_sorted);
    void*     planes = (void*)(ws + off_planes);

    int gN = (N + 255) / 256;
    triplane_transpose_f16<<<3 * 2048, 256, 0, stream>>>(fm, (uint4*)planes);
    zero_u32<<<(2 * NCELLS + 255) / 256, 256, 0, stream>>>(hist, 2 * NCELLS);
    cell_hist<<<gN, 256, 0, stream>>>(xyz, N, cellid, hist);
    scan_cells<<<1, 1024, 0, stream>>>(hist, cursor);
    cell_scatter<<<gN, 256, 0, stream>>>(xyz, cellid, cursor, sorted, N);
    triplane_gather_sorted<<<grid, 256, 0, stream>>>(sorted, planes, out, n12, grid);
  } else if (ws_size >= sz_planes) {
    triplane_transpose_f16<<<3 * 2048, 256, 0, stream>>>(fm, (uint4*)d_ws);
    triplane_gather<true><<<grid, 256, 0, stream>>>(xyz, d_ws, out, n12);
  } else {
    triplane_gather<false><<<grid, 256, 0, stream>>>(xyz, fm, out, n12);
  }
}